// Round 6
// baseline (420.028 us; speedup 1.0000x reference)
//
#include <hip/hip_runtime.h>
#include <hip/hip_bf16.h>

// 2-layer LSTM (H=32, T=512, I=1) + FC(1) + ReLU, fused, layer-pipelined at
// t4 granularity, NBW=8. Block = 128 threads = 2 waves: wave 0 = layer 0,
// wave 1 = layer 1 four steps behind (double-buffered LDS handoff, one
// __syncthreads per 4 steps). MFMA 16x16x32 bf16; col = q*8 + s (8 batches,
// 2-way replication). Weight-row permutation puts gate (tau, 8m+4q+r) at
// slot (2tau+q, r) -> 1 cndmask per gate value. Bias rides in MFMA C-in.
// sigma(i)*tanh(g) and sigma(o)*tanh(c) fused to share one rcp (8 trans/unit).
// h B-fragment: 2 cvt_pk + 2 ds_swizzle(xor8) + 4 cndmask. x prefetched.

typedef __attribute__((ext_vector_type(8))) short bf16x8;
typedef __attribute__((ext_vector_type(4))) float f32x4;
typedef __attribute__((ext_vector_type(4))) int   i32x4;

#define HID 32
#define SEQ 512
#define NT4 (SEQ / 4)
#define NBW 8
#define L2E 1.4426950408889634f

static __device__ __forceinline__ float fexp2(float x){ return __builtin_amdgcn_exp2f(x); }
static __device__ __forceinline__ float frcp (float x){ return __builtin_amdgcn_rcpf(x); }
static __device__ __forceinline__ short f2bf(float f){
  unsigned u = __builtin_bit_cast(unsigned, f);
  u = (u + 0x7fffu + ((u >> 16) & 1u)) >> 16;
  return (short)u;
}

// gate (tau, unit 8m+4q+r) lives at A[2*tau + q][r]  (1 cndmask, qb per-lane)
#define SEL1(tau, r) (qb ? A[2*(tau)+1][r] : A[2*(tau)][r])

__global__ __launch_bounds__(128, 1) void lstm2_nbw8_kernel(
    const float* __restrict__ x,
    const float* __restrict__ Wih0, const float* __restrict__ Whh0,
    const float* __restrict__ bih0, const float* __restrict__ bhh0,
    const float* __restrict__ Wih1, const float* __restrict__ Whh1,
    const float* __restrict__ bih1, const float* __restrict__ bhh1,
    const float* __restrict__ Wfc, const float* __restrict__ bfc,
    float* __restrict__ out)
{
  const int tid = threadIdx.x;
  const int w   = tid >> 6;        // 0: layer-0 producer, 1: layer-1 consumer
  const int l   = tid & 63;
  const int m   = l >> 4;          // A/B fragment k-group
  const int col = l & 15;          // MFMA N col = q*8 + s
  const int q   = col >> 3;        // replica -> owns units 8m+4q+{0..3}
  const int s   = col & 7;         // batch slot
  const int batch = blockIdx.x * NBW + s;
  const bool qb = (q != 0);

  __shared__ i32x4 hbuf[2][4][64];   // double-buffered 4-step h0 B-frags, 8 KiB

  // ---- weight fragments (A), rows pre-scaled: i,f,o -> -log2e; g -> +2log2e
  bf16x8 wfA[8], wfB[8];   // w0: wfA=Whh0; w1: wfA=Wih1, wfB=Whh1
  f32x4 cb[8];             // MFMA C-in: per-slot gate bias (pre-scaled)
  #pragma unroll
  for (int c = 0; c < 8; ++c) {
    const int tau = c >> 1, kh = c & 1;
    const float sc = (tau == 2) ? (2.0f * L2E) : (-L2E);
    const int ga = tau * 32 + (col >> 2) * 8 + kh * 4 + (col & 3); // A-row = col
    if (w == 0) {
      #pragma unroll
      for (int j = 0; j < 8; ++j)
        wfA[c][j] = f2bf(sc * Whh0[ga * HID + (m * 8 + j)]);
    } else {
      #pragma unroll
      for (int j = 0; j < 8; ++j) {
        wfA[c][j] = f2bf(sc * Wih1[ga * HID + (m * 8 + j)]);
        wfB[c][j] = f2bf(sc * Whh1[ga * HID + (m * 8 + j)]);
      }
    }
    #pragma unroll
    for (int r = 0; r < 4; ++r) {    // bias of gate at slot (c,r): unit 8m+4kh+r
      const int g = tau * 32 + 8 * m + 4 * kh + r;
      cb[c][r] = sc * (w == 0 ? (bih0[g] + bhh0[g]) : (bih1[g] + bhh1[g]));
    }
  }

  // ---- per-lane per-owned-unit constants (units u = 8m+4q+r)
  float w0x[4][4];   // w0: sc * Wih0[tau*32+u]
  float wfcr[4];     // w1: FC weights
  if (w == 0) {
    #pragma unroll
    for (int tau = 0; tau < 4; ++tau) {
      const float sc = (tau == 2) ? (2.0f * L2E) : (-L2E);
      #pragma unroll
      for (int r = 0; r < 4; ++r)
        w0x[tau][r] = sc * Wih0[tau * 32 + 8 * m + 4 * q + r];
    }
  } else {
    #pragma unroll
    for (int r = 0; r < 4; ++r) wfcr[r] = Wfc[8 * m + 4 * q + r];
  }

  bf16x8 hf = {};                 // w0: own h0 frag; w1: own h1 frag
  float cv[4] = {0.f, 0.f, 0.f, 0.f};
  float hrl[4] = {0.f, 0.f, 0.f, 0.f};

  const float* xb = x + (size_t)batch * SEQ;
  float4 xcur = {0.f, 0.f, 0.f, 0.f};
  if (w == 0) xcur = *reinterpret_cast<const float4*>(xb);

  for (int k = 0; k <= NT4; ++k) {
    float4 xnext = {0.f, 0.f, 0.f, 0.f};
    if (w == 0 && k + 1 < NT4)
      xnext = *reinterpret_cast<const float4*>(xb + (k + 1) * 4);  // prefetch

    if (w == 0 && k < NT4) {
      // ---------- producer: 4 steps of layer 0 into set k&1 ----------
      #pragma unroll
      for (int uu = 0; uu < 4; ++uu) {
        const float xt = (uu == 0) ? xcur.x : (uu == 1) ? xcur.y
                       : (uu == 2) ? xcur.z : xcur.w;
        f32x4 A[8];
        #pragma unroll
        for (int c = 0; c < 8; ++c)   // D = Whh0*h0 + bias (C-in)
          A[c] = __builtin_amdgcn_mfma_f32_16x16x32_bf16(wfA[c], hf, cb[c], 0, 0, 0);
        float hr[4];
        #pragma unroll
        for (int r = 0; r < 4; ++r) {
          const float gi = fmaf(w0x[0][r], xt, SEL1(0, r));
          const float gf = fmaf(w0x[1][r], xt, SEL1(1, r));
          const float gg = fmaf(w0x[2][r], xt, SEL1(2, r));
          const float go = fmaf(w0x[3][r], xt, SEL1(3, r));
          const float I = fexp2(gi), G = fexp2(gg);
          const float F = fexp2(gf), O = fexp2(go);
          const float fv = frcp(1.f + F);
          const float ig = (G - 1.f) * frcp((1.f + I) * (1.f + G)); // sig(i)*tanh(g)
          cv[r] = fmaf(fv, cv[r], ig);
          const float C2 = fexp2(cv[r] * (2.f * L2E));
          hr[r] = (C2 - 1.f) * frcp((1.f + O) * (1.f + C2));        // sig(o)*tanh(c)
        }
        int pk0, pk1;
        asm("v_cvt_pk_bf16_f32 %0, %1, %2" : "=v"(pk0) : "v"(hr[0]), "v"(hr[1]));
        asm("v_cvt_pk_bf16_f32 %0, %1, %2" : "=v"(pk1) : "v"(hr[2]), "v"(hr[3]));
        const int sw0 = __builtin_amdgcn_ds_swizzle(pk0, 0x201F);  // lane ^ 8
        const int sw1 = __builtin_amdgcn_ds_swizzle(pk1, 0x201F);
        i32x4 hd;
        hd[0] = qb ? sw0 : pk0;   // pair 4m+0
        hd[1] = qb ? sw1 : pk1;   // pair 4m+1
        hd[2] = qb ? pk0 : sw0;   // pair 4m+2
        hd[3] = qb ? pk1 : sw1;   // pair 4m+3
        hf = __builtin_bit_cast(bf16x8, hd);
        hbuf[k & 1][uu][l] = hd;       // publish B-fragment for wave 1
      }
    }
    if (w == 1 && k > 0) {
      // ---------- consumer: 4 steps of layer 1 from set (k-1)&1 ----------
      i32x4 hd4[4];
      #pragma unroll
      for (int uu = 0; uu < 4; ++uu) hd4[uu] = hbuf[(k - 1) & 1][uu][l];
      #pragma unroll
      for (int uu = 0; uu < 4; ++uu) {
        const bf16x8 h0f = __builtin_bit_cast(bf16x8, hd4[uu]);
        f32x4 A[8];
        #pragma unroll
        for (int c = 0; c < 8; ++c)   // recurrent (register-only) MFMA first
          A[c] = __builtin_amdgcn_mfma_f32_16x16x32_bf16(wfB[c], hf, cb[c], 0, 0, 0);
        #pragma unroll
        for (int c = 0; c < 8; ++c)   // LDS-dependent MFMA second
          A[c] = __builtin_amdgcn_mfma_f32_16x16x32_bf16(wfA[c], h0f, A[c], 0, 0, 0);
        #pragma unroll
        for (int r = 0; r < 4; ++r) {
          const float gi = SEL1(0, r);
          const float gf = SEL1(1, r);
          const float gg = SEL1(2, r);
          const float go = SEL1(3, r);
          const float I = fexp2(gi), G = fexp2(gg);
          const float F = fexp2(gf), O = fexp2(go);
          const float fv = frcp(1.f + F);
          const float ig = (G - 1.f) * frcp((1.f + I) * (1.f + G));
          cv[r] = fmaf(fv, cv[r], ig);
          const float C2 = fexp2(cv[r] * (2.f * L2E));
          hrl[r] = (C2 - 1.f) * frcp((1.f + O) * (1.f + C2));
        }
        int pk0, pk1;
        asm("v_cvt_pk_bf16_f32 %0, %1, %2" : "=v"(pk0) : "v"(hrl[0]), "v"(hrl[1]));
        asm("v_cvt_pk_bf16_f32 %0, %1, %2" : "=v"(pk1) : "v"(hrl[2]), "v"(hrl[3]));
        const int sw0 = __builtin_amdgcn_ds_swizzle(pk0, 0x201F);
        const int sw1 = __builtin_amdgcn_ds_swizzle(pk1, 0x201F);
        i32x4 hd;
        hd[0] = qb ? sw0 : pk0;
        hd[1] = qb ? sw1 : pk1;
        hd[2] = qb ? pk0 : sw0;
        hd[3] = qb ? pk1 : sw1;
        hf = __builtin_bit_cast(bf16x8, hd);
      }
    }
    __syncthreads();
    xcur = xnext;
  }

  // ---- FC + ReLU (wave 1 holds h1(T-1) units 8m+4q+{0..3} in hrl) ----
  if (w == 1) {
    float part = hrl[0] * wfcr[0];
    part = fmaf(hrl[1], wfcr[1], part);
    part = fmaf(hrl[2], wfcr[2], part);
    part = fmaf(hrl[3], wfcr[3], part);
    part += __shfl_xor(part, 8);
    part += __shfl_xor(part, 16);
    part += __shfl_xor(part, 32);
    if (l < 8) {
      const float o = part + bfc[0];
      out[blockIdx.x * NBW + l] = o > 0.f ? o : 0.f;
    }
  }
}

extern "C" void kernel_launch(void* const* d_in, const int* in_sizes, int n_in,
                              void* d_out, int out_size, void* d_ws, size_t ws_size,
                              hipStream_t stream) {
  const float* x    = (const float*)d_in[0];
  const float* Wih0 = (const float*)d_in[1];
  const float* Whh0 = (const float*)d_in[2];
  const float* bih0 = (const float*)d_in[3];
  const float* bhh0 = (const float*)d_in[4];
  const float* Wih1 = (const float*)d_in[5];
  const float* Whh1 = (const float*)d_in[6];
  const float* bih1 = (const float*)d_in[7];
  const float* bhh1 = (const float*)d_in[8];
  const float* Wfc  = (const float*)d_in[9];
  const float* bfc  = (const float*)d_in[10];

  const int B = 4096;
  const int grid = B / NBW;   // 512 blocks x 2 waves -> 1 wave/SIMD
  lstm2_nbw8_kernel<<<grid, 128, 0, stream>>>(
      x, Wih0, Whh0, bih0, bhh0, Wih1, Whh1, bih1, bhh1, Wfc, bfc,
      (float*)d_out);
}

// Round 7
// 277.246 us; speedup vs baseline: 1.5150x; 1.5150x over previous
//
#include <hip/hip_runtime.h>
#include <hip/hip_bf16.h>

// 2-layer LSTM (H=32, T=512, I=1) + FC(1) + ReLU, fused, layer-pipelined at
// t4 granularity (R5 structure) + R6's shape-preserving issue cuts.
// Block = 128 threads = 2 waves: wave 0 = layer 0, wave 1 = layer 1 four
// steps behind (double-buffered LDS handoff, one __syncthreads per 4 steps).
// MFMA 16x16x32 bf16, NBW=4; lane (m,q,s) owns units 8m+2q+{0,1} of batch s;
// 3-cndmask gate select; cvt_pk + 4 ds_swizzle h reassembly.
// NEW: bias rides in MFMA C-in (cb); fused activations share rcp
// (8 trans/unit); x prefetched one t4 ahead; setprio around consumer MFMAs.

typedef __attribute__((ext_vector_type(8))) short bf16x8;
typedef __attribute__((ext_vector_type(4))) float f32x4;
typedef __attribute__((ext_vector_type(4))) int   i32x4;

#define HID 32
#define SEQ 512
#define NT4 (SEQ / 4)
#define NBW 4
#define L2E 1.4426950408889634f

static __device__ __forceinline__ float fexp2(float x){ return __builtin_amdgcn_exp2f(x); }
static __device__ __forceinline__ float frcp (float x){ return __builtin_amdgcn_rcpf(x); }
static __device__ __forceinline__ short f2bf(float f){
  unsigned u = __builtin_bit_cast(unsigned, f);
  u = (u + 0x7fffu + ((u >> 16) & 1u)) >> 16;
  return (short)u;
}

// gate (tau, unit 8m+2q+jj) lives at A[2*tau + (q>>1)][2*(q&1) + jj]
#define SEL(Atab, tau, jj) \
  ( khb ? ( rb ? Atab[2*(tau)+1][2+(jj)] : Atab[2*(tau)+1][(jj)] ) \
        : ( rb ? Atab[2*(tau)  ][2+(jj)] : Atab[2*(tau)  ][(jj)] ) )

// fused LSTM cell: gates pre-scaled (i,f,o by -log2e; g by +2log2e)
#define CELL(gi, gf, gg, go, cvr, hout) do {                         \
  const float I_ = fexp2(gi), G_ = fexp2(gg);                        \
  const float F_ = fexp2(gf), O_ = fexp2(go);                        \
  const float fv_ = frcp(1.f + F_);                                  \
  const float ig_ = (G_ - 1.f) * frcp((1.f + I_) * (1.f + G_));      \
  (cvr) = fmaf(fv_, (cvr), ig_);                                     \
  const float C2_ = fexp2((cvr) * (2.f * L2E));                      \
  (hout) = (C2_ - 1.f) * frcp((1.f + O_) * (1.f + C2_));             \
} while (0)

__global__ __launch_bounds__(128, 2) void lstm2_pipe4b_kernel(
    const float* __restrict__ x,
    const float* __restrict__ Wih0, const float* __restrict__ Whh0,
    const float* __restrict__ bih0, const float* __restrict__ bhh0,
    const float* __restrict__ Wih1, const float* __restrict__ Whh1,
    const float* __restrict__ bih1, const float* __restrict__ bhh1,
    const float* __restrict__ Wfc, const float* __restrict__ bfc,
    float* __restrict__ out)
{
  const int tid = threadIdx.x;
  const int w   = tid >> 6;        // 0: layer-0 producer, 1: layer-1 consumer
  const int l   = tid & 63;
  const int m   = l >> 4;          // A/B fragment k-group
  const int col = l & 15;          // MFMA N col
  const int q   = col >> 2;        // replication group -> units 8m+2q+{0,1}
  const int s   = col & 3;         // batch slot
  const int batch = blockIdx.x * NBW + s;
  const bool khb = ((q >> 1) & 1) != 0;
  const bool rb  = (q & 1) != 0;

  __shared__ i32x4 hbuf[2][4][64];   // double-buffered 4-step h0 B-frags, 8 KiB

  // ---- weight fragments (A), rows pre-scaled: i,f,o -> -log2e; g -> +2log2e
  bf16x8 wfA[8], wfB[8];   // w0: wfA=Whh0; w1: wfA=Wih1, wfB=Whh1
  f32x4 cb[8];             // MFMA C-in: per-slot gate bias (pre-scaled)
  #pragma unroll
  for (int c = 0; c < 8; ++c) {
    const int tau = c >> 1, kh = c & 1;
    const float sc = (tau == 2) ? (2.0f * L2E) : (-L2E);
    const int ga = tau * 32 + (q << 3) + (kh << 2) + s;   // A-row = col packing
    if (w == 0) {
      #pragma unroll
      for (int j = 0; j < 8; ++j)
        wfA[c][j] = f2bf(sc * Whh0[ga * HID + (m * 8 + j)]);
    } else {
      #pragma unroll
      for (int j = 0; j < 8; ++j) {
        wfA[c][j] = f2bf(sc * Wih1[ga * HID + (m * 8 + j)]);
        wfB[c][j] = f2bf(sc * Whh1[ga * HID + (m * 8 + j)]);
      }
    }
    #pragma unroll
    for (int r = 0; r < 4; ++r) {    // bias of D-slot (c,r): gate row below
      const int g = tau * 32 + 8 * m + 4 * kh + r;
      cb[c][r] = sc * (w == 0 ? (bih0[g] + bhh0[g]) : (bih1[g] + bhh1[g]));
    }
  }

  // ---- per-lane constants for owned units u = 8m+2q+jj
  float w0x[4][2];   // w0: sc * Wih0[tau*32+u]
  float wfcA = 0.f, wfcB = 0.f;
  if (w == 0) {
    #pragma unroll
    for (int tau = 0; tau < 4; ++tau) {
      const float sc = (tau == 2) ? (2.0f * L2E) : (-L2E);
      #pragma unroll
      for (int jj = 0; jj < 2; ++jj)
        w0x[tau][jj] = sc * Wih0[tau * 32 + 8 * m + 2 * q + jj];
    }
  } else {
    wfcA = Wfc[8 * m + 2 * q];
    wfcB = Wfc[8 * m + 2 * q + 1];
  }

  bf16x8 hf = {};                 // w0: own h0 frag; w1: own h1 frag
  float cv[2] = {0.f, 0.f};
  float hn0 = 0.f, hn1 = 0.f;

  const float* xb = x + (size_t)batch * SEQ;
  float4 xcur = {0.f, 0.f, 0.f, 0.f};
  if (w == 0) xcur = *reinterpret_cast<const float4*>(xb);

  for (int k = 0; k <= NT4; ++k) {
    float4 xnext = {0.f, 0.f, 0.f, 0.f};
    if (w == 0 && k + 1 < NT4)
      xnext = *reinterpret_cast<const float4*>(xb + (k + 1) * 4);  // prefetch

    if (w == 0 && k < NT4) {
      // ---------- producer: 4 steps of layer 0 into set k&1 ----------
      #pragma unroll
      for (int uu = 0; uu < 4; ++uu) {
        const float xt = (uu == 0) ? xcur.x : (uu == 1) ? xcur.y
                       : (uu == 2) ? xcur.z : xcur.w;
        f32x4 A[8];
        #pragma unroll
        for (int c = 0; c < 8; ++c)   // D = Whh0*h0 + bias (C-in)
          A[c] = __builtin_amdgcn_mfma_f32_16x16x32_bf16(wfA[c], hf, cb[c], 0, 0, 0);
        #pragma unroll
        for (int jj = 0; jj < 2; ++jj) {
          const float gi = fmaf(w0x[0][jj], xt, SEL(A, 0, jj));
          const float gf = fmaf(w0x[1][jj], xt, SEL(A, 1, jj));
          const float gg = fmaf(w0x[2][jj], xt, SEL(A, 2, jj));
          const float go = fmaf(w0x[3][jj], xt, SEL(A, 3, jj));
          float hn;
          CELL(gi, gf, gg, go, cv[jj], hn);
          if (jj == 0) hn0 = hn; else hn1 = hn;
        }
        int pk;
        asm("v_cvt_pk_bf16_f32 %0, %1, %2" : "=v"(pk) : "v"(hn0), "v"(hn1));
        i32x4 hd;
        hd[0] = __builtin_amdgcn_ds_swizzle(pk, 0x013);
        hd[1] = __builtin_amdgcn_ds_swizzle(pk, 0x093);
        hd[2] = __builtin_amdgcn_ds_swizzle(pk, 0x113);
        hd[3] = __builtin_amdgcn_ds_swizzle(pk, 0x193);
        hf = __builtin_bit_cast(bf16x8, hd);
        hbuf[k & 1][uu][l] = hd;       // publish B-fragment for wave 1
      }
    }
    if (w == 1 && k > 0) {
      // ---------- consumer: 4 steps of layer 1 from set (k-1)&1 ----------
      i32x4 hd4[4];
      #pragma unroll
      for (int uu = 0; uu < 4; ++uu) hd4[uu] = hbuf[(k - 1) & 1][uu][l];
      #pragma unroll
      for (int uu = 0; uu < 4; ++uu) {
        const bf16x8 h0f = __builtin_bit_cast(bf16x8, hd4[uu]);
        f32x4 A[8];
        __builtin_amdgcn_s_setprio(1);
        #pragma unroll
        for (int c = 0; c < 8; ++c)   // recurrent (register-only) MFMA first
          A[c] = __builtin_amdgcn_mfma_f32_16x16x32_bf16(wfB[c], hf, cb[c], 0, 0, 0);
        #pragma unroll
        for (int c = 0; c < 8; ++c)   // LDS-dependent MFMA second
          A[c] = __builtin_amdgcn_mfma_f32_16x16x32_bf16(wfA[c], h0f, A[c], 0, 0, 0);
        __builtin_amdgcn_s_setprio(0);
        #pragma unroll
        for (int jj = 0; jj < 2; ++jj) {
          const float gi = SEL(A, 0, jj);
          const float gf = SEL(A, 1, jj);
          const float gg = SEL(A, 2, jj);
          const float go = SEL(A, 3, jj);
          float hn;
          CELL(gi, gf, gg, go, cv[jj], hn);
          if (jj == 0) hn0 = hn; else hn1 = hn;
        }
        int pk;
        asm("v_cvt_pk_bf16_f32 %0, %1, %2" : "=v"(pk) : "v"(hn0), "v"(hn1));
        i32x4 hd1;
        hd1[0] = __builtin_amdgcn_ds_swizzle(pk, 0x013);
        hd1[1] = __builtin_amdgcn_ds_swizzle(pk, 0x093);
        hd1[2] = __builtin_amdgcn_ds_swizzle(pk, 0x113);
        hd1[3] = __builtin_amdgcn_ds_swizzle(pk, 0x193);
        hf = __builtin_bit_cast(bf16x8, hd1);
      }
    }
    __syncthreads();
    xcur = xnext;
  }

  // ---- FC + ReLU (wave 1 holds h1(T-1) in hn0/hn1) ----
  if (w == 1) {
    float part = hn0 * wfcA + hn1 * wfcB;
    part += __shfl_xor(part, 4);
    part += __shfl_xor(part, 8);
    part += __shfl_xor(part, 16);
    part += __shfl_xor(part, 32);
    if (l < 4) {
      const float o = part + bfc[0];
      out[blockIdx.x * NBW + l] = o > 0.f ? o : 0.f;
    }
  }
}

extern "C" void kernel_launch(void* const* d_in, const int* in_sizes, int n_in,
                              void* d_out, int out_size, void* d_ws, size_t ws_size,
                              hipStream_t stream) {
  const float* x    = (const float*)d_in[0];
  const float* Wih0 = (const float*)d_in[1];
  const float* Whh0 = (const float*)d_in[2];
  const float* bih0 = (const float*)d_in[3];
  const float* bhh0 = (const float*)d_in[4];
  const float* Wih1 = (const float*)d_in[5];
  const float* Whh1 = (const float*)d_in[6];
  const float* bih1 = (const float*)d_in[7];
  const float* bhh1 = (const float*)d_in[8];
  const float* Wfc  = (const float*)d_in[9];
  const float* bfc  = (const float*)d_in[10];

  const int B = 4096;
  const int grid = B / NBW;   // 1024 blocks x 2 waves -> 2 waves/SIMD
  lstm2_pipe4b_kernel<<<grid, 128, 0, stream>>>(
      x, Wih0, Whh0, bih0, bhh0, Wih1, Whh1, bih1, bhh1, Wfc, bfc,
      (float*)d_out);
}